// Round 5
// baseline (532.441 us; speedup 1.0000x reference)
//
#include <hip/hip_runtime.h>
#include <hip/hip_bf16.h>
#include <stdint.h>

#define B_ 8
#define NH_ 12
#define NBH (B_*NH_)       // 96
#define T_ 1024
#define D_ 256
#define QBLK 128           // q rows per block (4 waves x 32)
#define QW 32              // q rows per wave
#define KVB 32             // kv tile
#define NKV (T_/KVB)       // 32
#define NQB (T_/QBLK)      // 8
#define NBLK (NBH*NQB)     // 768

typedef __attribute__((ext_vector_type(8))) short bf16x8;
typedef __attribute__((ext_vector_type(16))) float f32x16;
typedef unsigned short ushort_t;

#define Z16 ((f32x16){0,0,0,0,0,0,0,0,0,0,0,0,0,0,0,0})

// KR pre-scale: 0.25 * sqrt(log2(e)) so that (KR.KR) = (S/sqrt(256)) * log2(e)
#define KSCALE 0.30028060218f

__device__ __forceinline__ short f2bf(float x) {
  __hip_bfloat16 h = __float2bfloat16(x);
  return *reinterpret_cast<short*>(&h);
}
__device__ __forceinline__ void gload16(const ushort_t* g, ushort_t* l) {
  __builtin_amdgcn_global_load_lds(
      (const __attribute__((address_space(1))) uint32_t*)g,
      (__attribute__((address_space(3))) uint32_t*)l, 16, 0, 0);
}
__device__ __forceinline__ float hmax16(f32x16 v) {
  float a0 = fmaxf(v[0], v[1]),  a1 = fmaxf(v[2], v[3]);
  float a2 = fmaxf(v[4], v[5]),  a3 = fmaxf(v[6], v[7]);
  float a4 = fmaxf(v[8], v[9]),  a5 = fmaxf(v[10], v[11]);
  float a6 = fmaxf(v[12], v[13]), a7 = fmaxf(v[14], v[15]);
  float b0 = fmaxf(a0, a1), b1 = fmaxf(a2, a3), b2 = fmaxf(a4, a5), b3 = fmaxf(a6, a7);
  return fmaxf(fmaxf(b0, b1), fmaxf(b2, b3));
}

// ---------------- prep kernels ----------------

__global__ void tab_kernel(const float* __restrict__ freqs, float2* __restrict__ tab) {
  int idx = blockIdx.x * blockDim.x + threadIdx.x;
  if (idx >= T_ * (D_/2)) return;
  int t = idx >> 7;
  int i = idx & 127;
  float ph = (float)t * freqs[2*i];
  ph -= floorf(ph);
  float ang = ph * 6.283185307179586f;
  tab[idx] = make_float2(cosf(ang), sinf(ang));
}

// KR[row][d] = rope(Q)[row][d] * KSCALE  (bf16). row = bh*T + t.
__global__ __launch_bounds__(256) void kr_kernel(const float* __restrict__ Q,
                                                 const float2* __restrict__ tab,
                                                 ushort_t* __restrict__ KR) {
  int row = blockIdx.x * 8 + (threadIdx.x >> 5);
  int d8  = threadIdx.x & 31;
  int t = row & (T_ - 1);
  const float* src = Q + (size_t)row * D_ + d8 * 8;
  float4 x0 = *(const float4*)src;
  float4 x1 = *(const float4*)(src + 4);
  const float2* tr = tab + t * (D_/2) + d8 * 4;
  float2 c0 = tr[0], c1 = tr[1], c2 = tr[2], c3 = tr[3];
  bf16x8 f;
  f[0] = f2bf((x0.x * c0.x - x0.y * c0.y) * KSCALE);
  f[1] = f2bf((x0.y * c0.x + x0.x * c0.y) * KSCALE);
  f[2] = f2bf((x0.z * c1.x - x0.w * c1.y) * KSCALE);
  f[3] = f2bf((x0.w * c1.x + x0.z * c1.y) * KSCALE);
  f[4] = f2bf((x1.x * c2.x - x1.y * c2.y) * KSCALE);
  f[5] = f2bf((x1.y * c2.x + x1.x * c2.y) * KSCALE);
  f[6] = f2bf((x1.z * c3.x - x1.w * c3.y) * KSCALE);
  f[7] = f2bf((x1.w * c3.x + x1.z * c3.y) * KSCALE);
  *(bf16x8*)(KR + (size_t)row * D_ + d8 * 8) = f;
}

// VT[bh][d][t] = bf16(V[bh][t][d]) via 64x64 LDS tile transpose
__global__ __launch_bounds__(256) void vt_kernel(const float* __restrict__ V,
                                                 ushort_t* __restrict__ VT) {
  int blk = blockIdx.x;
  int d64 = blk & 3, t64 = (blk >> 2) & 15, bh = blk >> 6;
  __shared__ ushort_t st[64][66];
  {
    int t = threadIdx.x >> 2, j = threadIdx.x & 3;
    const float* src = V + ((size_t)bh * T_ + t64 * 64 + t) * D_ + d64 * 64 + j * 16;
#pragma unroll
    for (int q2 = 0; q2 < 4; ++q2) {
      float4 x = *(const float4*)(src + q2 * 4);
      st[t][j*16 + q2*4 + 0] = (ushort_t)f2bf(x.x);
      st[t][j*16 + q2*4 + 1] = (ushort_t)f2bf(x.y);
      st[t][j*16 + q2*4 + 2] = (ushort_t)f2bf(x.z);
      st[t][j*16 + q2*4 + 3] = (ushort_t)f2bf(x.w);
    }
  }
  __syncthreads();
  {
    int d = threadIdx.x >> 2, tq = threadIdx.x & 3;
    bf16x8 a_, b_;
#pragma unroll
    for (int i = 0; i < 8; ++i) {
      a_[i] = (short)st[tq*16 + i][d];
      b_[i] = (short)st[tq*16 + 8 + i][d];
    }
    ushort_t* dst = VT + ((size_t)bh * D_ + d64*64 + d) * T_ + t64*64 + tq*16;
    *(bf16x8*)dst = a_;
    *(bf16x8*)(dst + 8) = b_;
  }
}

// ---------------- attention kernel ----------------
// Counted-vmcnt double-buffer schedule (T4): per iteration
//   stage(t+1) -> s_waitcnt vmcnt(8) -> s_barrier -> compute(t) -> s_barrier
// vmcnt(8): the 8 loads just issued may stay in flight; the 8 for tile t
// (issued last iteration) are complete (FIFO retirement). Barrier-1 makes that
// global (RAW); barrier-2 protects against next iteration's staging (WAR).
// Reductions across lane^32 use __shfl_xor (proven); permlane asm is only used
// for the P-fragment build where operands are provably distinct (r3-proven).
#define ATTN_ITER(STG, TT, KC, VC, KN, VN)                                     \
  {                                                                            \
    if (STG) {                                                                 \
      const ushort_t* Ks_ = KRb + (size_t)((TT) + 1) * (KVB * D_);             \
      const ushort_t* Vs_ = VTb + (size_t)((TT) + 1) * KVB;                    \
      _Pragma("unroll")                                                        \
      for (int i = 0; i < 4; ++i) {                                            \
        gload16(Ks_ + koff[i], &KN[((i * 4 + wv) * 64) * 8]);                  \
        gload16(Vs_ + voff[i], &VN[((i * 4 + wv) * 64) * 8]);                  \
      }                                                                        \
      asm volatile("s_waitcnt vmcnt(8)" ::: "memory");                         \
    } else {                                                                   \
      asm volatile("s_waitcnt vmcnt(0)" ::: "memory");                         \
    }                                                                          \
    __builtin_amdgcn_s_barrier();                                              \
    asm volatile("" ::: "memory");                                             \
    __builtin_amdgcn_sched_barrier(0);  /* nothing crosses the barrier */      \
    f32x16 s0_ = Z16, s1_ = Z16, s2_ = Z16, s3_ = Z16;                         \
    __builtin_amdgcn_s_setprio(1);                                             \
    _Pragma("unroll")                                                          \
    for (int m = 0; m < 16; m += 4) {                                          \
      bf16x8 kfa_ = *(const bf16x8*)&KC[lo * 256 + (((2*m + hi)     ^ (lo & 7)) * 8)]; \
      bf16x8 kfb_ = *(const bf16x8*)&KC[lo * 256 + (((2*m + 2 + hi) ^ (lo & 7)) * 8)]; \
      bf16x8 kfc_ = *(const bf16x8*)&KC[lo * 256 + (((2*m + 4 + hi) ^ (lo & 7)) * 8)]; \
      bf16x8 kfd_ = *(const bf16x8*)&KC[lo * 256 + (((2*m + 6 + hi) ^ (lo & 7)) * 8)]; \
      s0_ = __builtin_amdgcn_mfma_f32_32x32x16_bf16(kfa_, qf[m],   s0_, 0, 0, 0); \
      s1_ = __builtin_amdgcn_mfma_f32_32x32x16_bf16(kfb_, qf[m+1], s1_, 0, 0, 0); \
      s2_ = __builtin_amdgcn_mfma_f32_32x32x16_bf16(kfc_, qf[m+2], s2_, 0, 0, 0); \
      s3_ = __builtin_amdgcn_mfma_f32_32x32x16_bf16(kfd_, qf[m+3], s3_, 0, 0, 0); \
    }                                                                          \
    __builtin_amdgcn_s_setprio(0);                                             \
    f32x16 sacc_ = (s0_ + s1_) + (s2_ + s3_);                                  \
    float pm_ = hmax16(sacc_);                                                 \
    pm_ = fmaxf(pm_, __shfl_xor(pm_, 32));                                     \
    if (!__all(pm_ <= mR + 8.0f)) {                                            \
      float nm_ = fmaxf(mR, pm_);                                              \
      float corr_ = exp2f(mR - nm_);                                           \
      mR = nm_;                                                                \
      lR *= corr_;                                                             \
      if (hi == 0) bcw[lo] = corr_;                                            \
      asm volatile("s_waitcnt lgkmcnt(0)" ::: "memory");                       \
      _Pragma("unroll")                                                        \
      for (int g2 = 0; g2 < 4; ++g2) {                                         \
        float4 cr_ = *(const float4*)&bcw[g2 * 8 + hi * 4];                    \
        _Pragma("unroll")                                                      \
        for (int dt = 0; dt < 8; ++dt) {                                       \
          oacc[dt][g2*4 + 0] *= cr_.x;                                         \
          oacc[dt][g2*4 + 1] *= cr_.y;                                         \
          oacc[dt][g2*4 + 2] *= cr_.z;                                         \
          oacc[dt][g2*4 + 3] *= cr_.w;                                         \
        }                                                                      \
      }                                                                        \
    }                                                                          \
    float p_[16];                                                              \
    _Pragma("unroll")                                                          \
    for (int r = 0; r < 16; ++r) p_[r] = exp2f(sacc_[r] - mR);                 \
    float ps_ = (((p_[0]+p_[1]) + (p_[2]+p_[3])) + ((p_[4]+p_[5]) + (p_[6]+p_[7]))) \
              + (((p_[8]+p_[9]) + (p_[10]+p_[11])) + ((p_[12]+p_[13]) + (p_[14]+p_[15]))); \
    ps_ += __shfl_xor(ps_, 32);                                                \
    lR += ps_;                                                                 \
    unsigned int c00_, c01_, c10_, c11_, c20_, c21_, c30_, c31_;               \
    asm("v_cvt_pk_bf16_f32 %0, %1, %2" : "=v"(c00_) : "v"(p_[0]),  "v"(p_[1])); \
    asm("v_cvt_pk_bf16_f32 %0, %1, %2" : "=v"(c01_) : "v"(p_[2]),  "v"(p_[3])); \
    asm("v_cvt_pk_bf16_f32 %0, %1, %2" : "=v"(c10_) : "v"(p_[4]),  "v"(p_[5])); \
    asm("v_cvt_pk_bf16_f32 %0, %1, %2" : "=v"(c11_) : "v"(p_[6]),  "v"(p_[7])); \
    asm("v_cvt_pk_bf16_f32 %0, %1, %2" : "=v"(c20_) : "v"(p_[8]),  "v"(p_[9])); \
    asm("v_cvt_pk_bf16_f32 %0, %1, %2" : "=v"(c21_) : "v"(p_[10]), "v"(p_[11])); \
    asm("v_cvt_pk_bf16_f32 %0, %1, %2" : "=v"(c30_) : "v"(p_[12]), "v"(p_[13])); \
    asm("v_cvt_pk_bf16_f32 %0, %1, %2" : "=v"(c31_) : "v"(p_[14]), "v"(p_[15])); \
    asm("v_permlane32_swap_b32 %0, %1" : "+v"(c00_), "+v"(c10_));              \
    asm("v_permlane32_swap_b32 %0, %1" : "+v"(c01_), "+v"(c11_));              \
    asm("v_permlane32_swap_b32 %0, %1" : "+v"(c20_), "+v"(c30_));              \
    asm("v_permlane32_swap_b32 %0, %1" : "+v"(c21_), "+v"(c31_));              \
    bf16x8 pA_, pB_;                                                           \
    {                                                                          \
      union { unsigned int u[4]; bf16x8 v; } tA_, tB_;                         \
      tA_.u[0] = c00_; tA_.u[1] = c01_; tA_.u[2] = c10_; tA_.u[3] = c11_;      \
      tB_.u[0] = c20_; tB_.u[1] = c21_; tB_.u[2] = c30_; tB_.u[3] = c31_;      \
      pA_ = tA_.v; pB_ = tB_.v;                                                \
    }                                                                          \
    __builtin_amdgcn_s_setprio(1);                                             \
    _Pragma("unroll")                                                          \
    for (int dt = 0; dt < 8; ++dt) {                                           \
      bf16x8 vf0_ = *(const bf16x8*)&VC[(dt*32 + lo) * 32 + ((hi ^ vswz) * 8)]; \
      oacc[dt] = __builtin_amdgcn_mfma_f32_32x32x16_bf16(pA_, vf0_, oacc[dt], 0, 0, 0); \
      bf16x8 vf1_ = *(const bf16x8*)&VC[(dt*32 + lo) * 32 + (((2 + hi) ^ vswz) * 8)]; \
      oacc[dt] = __builtin_amdgcn_mfma_f32_32x32x16_bf16(pB_, vf1_, oacc[dt], 0, 0, 0); \
    }                                                                          \
    __builtin_amdgcn_s_setprio(0);                                             \
    __builtin_amdgcn_sched_barrier(0);                                         \
    asm volatile("" ::: "memory");                                             \
    __builtin_amdgcn_s_barrier();                                              \
  }

__global__ __launch_bounds__(256, 2)
void attn5(const ushort_t* __restrict__ KR, const ushort_t* __restrict__ VT,
           float* __restrict__ O) {
  int bid = blockIdx.x;
  int swz = (bid & 7) * (NBLK / 8) + (bid >> 3);   // bijective: 768 % 8 == 0
  int qb = swz & (NQB - 1);
  int bh = swz >> 3;

  const ushort_t* __restrict__ KRb = KR + (size_t)bh * T_ * D_;
  const ushort_t* __restrict__ VTb = VT + (size_t)bh * D_ * T_;
  float* __restrict__ Ob = O + (size_t)bh * T_ * D_;

  const int tid = threadIdx.x, lane = tid & 63, wv = tid >> 6;
  const int lo = lane & 31, hi = lane >> 5;
  const int vswz = (lo >> 1) & 3;
  const int q0 = qb * QBLK + wv * QW;

  __shared__ __align__(16) ushort_t Kb0[KVB * D_];
  __shared__ __align__(16) ushort_t Kb1[KVB * D_];
  __shared__ __align__(16) ushort_t Vb0[D_ * KVB];
  __shared__ __align__(16) ushort_t Vb1[D_ * KVB];
  __shared__ __align__(16) float bc[4][32];

  float* bcw = bc[wv];

  // stage address maps (per lane, constant across tiles; inverse-swizzled source)
  int koff[4], voff[4];
#pragma unroll
  for (int i = 0; i < 4; ++i) {
    int ch = (i * 4 + wv) * 64 + lane;
    int r = ch >> 5, c = ch & 31;
    koff[i] = r * 256 + ((c ^ (r & 7)) * 8);
    int d = ch >> 2, c2 = ch & 3;
    voff[i] = d * 1024 + ((c2 ^ ((d >> 1) & 3)) * 8);
  }

  // resident Q fragments (rows of KR; KSCALE pre-applied on both operands)
  bf16x8 qf[16];
  {
    const ushort_t* qrow = KRb + (size_t)(q0 + lo) * D_ + hi * 8;
#pragma unroll
    for (int m = 0; m < 16; ++m) qf[m] = *(const bf16x8*)(qrow + m * 16);
  }

  f32x16 oacc[8];
#pragma unroll
  for (int dt = 0; dt < 8; ++dt) oacc[dt] = Z16;
  float mR = -1e30f, lR = 0.0f;

  // prologue: stage tile 0 into buffer 0 (iter 0's vmcnt+barrier covers it)
#pragma unroll
  for (int i = 0; i < 4; ++i) {
    gload16(KRb + koff[i], &Kb0[((i * 4 + wv) * 64) * 8]);
    gload16(VTb + voff[i], &Vb0[((i * 4 + wv) * 64) * 8]);
  }

  for (int t = 0; t + 2 < NKV; t += 2) {
    ATTN_ITER(1, t,     Kb0, Vb0, Kb1, Vb1);
    ATTN_ITER(1, t + 1, Kb1, Vb1, Kb0, Vb0);
  }
  ATTN_ITER(1, NKV - 2, Kb0, Vb0, Kb1, Vb1);
  ATTN_ITER(0, NKV - 1, Kb1, Vb1, Kb0, Vb0);

  // epilogue: broadcast 1/l per q-row, normalize, store
  if (hi == 0) bcw[lo] = 1.0f / lR;
  asm volatile("s_waitcnt lgkmcnt(0)" ::: "memory");
#pragma unroll
  for (int g2 = 0; g2 < 4; ++g2) {
    float4 il = *(const float4*)&bcw[g2 * 8 + hi * 4];
#pragma unroll
    for (int j = 0; j < 4; ++j) {
      int r = g2 * 4 + j;
      int qr = j + 8 * g2 + 4 * hi;
      float sc = (j == 0) ? il.x : (j == 1) ? il.y : (j == 2) ? il.z : il.w;
#pragma unroll
      for (int dt = 0; dt < 8; ++dt)
        Ob[(size_t)(q0 + qr) * D_ + dt * 32 + lo] = oacc[dt][r] * sc;
    }
  }
}

extern "C" void kernel_launch(void* const* d_in, const int* in_sizes, int n_in,
                              void* d_out, int out_size, void* d_ws, size_t ws_size,
                              hipStream_t stream) {
  const float* Q     = (const float*)d_in[0];
  const float* V     = (const float*)d_in[1];
  const float* freqs = (const float*)d_in[2];
  float* Out = (float*)d_out;

  float2* tab  = (float2*)d_ws;                                   // 1 MB
  ushort_t* KR = (ushort_t*)((char*)d_ws + (1 << 20));            // 48 MB
  ushort_t* VT = (ushort_t*)((char*)d_ws + (1 << 20) + (size_t)NBH * T_ * D_ * 2);  // 48 MB

  tab_kernel<<<(T_ * (D_/2) + 255) / 256, 256, 0, stream>>>(freqs, tab);
  kr_kernel<<<NBH * T_ / 8, 256, 0, stream>>>(Q, tab, KR);
  vt_kernel<<<NBH * 16 * 4, 256, 0, stream>>>(V, VT);
  attn5<<<NBLK, 256, 0, stream>>>(KR, VT, Out);
}

// Round 6
// 505.992 us; speedup vs baseline: 1.0523x; 1.0523x over previous
//
#include <hip/hip_runtime.h>
#include <hip/hip_bf16.h>
#include <stdint.h>

#define B_ 8
#define NH_ 12
#define NBH (B_*NH_)       // 96
#define T_ 1024
#define D_ 256
#define QBLK 256           // q rows per block (8 waves x 32)
#define QW 32              // q rows per wave
#define KVB 32             // kv tile
#define NKV (T_/KVB)       // 32
#define NQB (T_/QBLK)      // 4
#define NBLK (NBH*NQB)     // 384

typedef __attribute__((ext_vector_type(8))) short bf16x8;
typedef __attribute__((ext_vector_type(16))) float f32x16;
typedef unsigned short ushort_t;

#define Z16 ((f32x16){0,0,0,0,0,0,0,0,0,0,0,0,0,0,0,0})

// KR pre-scale: 0.25 * sqrt(log2(e)) so that (KR.KR) = (S/sqrt(256)) * log2(e)
#define KSCALE 0.30028060218f

__device__ __forceinline__ short f2bf(float x) {
  __hip_bfloat16 h = __float2bfloat16(x);
  return *reinterpret_cast<short*>(&h);
}
__device__ __forceinline__ void gload16(const ushort_t* g, ushort_t* l) {
  __builtin_amdgcn_global_load_lds(
      (const __attribute__((address_space(1))) uint32_t*)g,
      (__attribute__((address_space(3))) uint32_t*)l, 16, 0, 0);
}
__device__ __forceinline__ float hmax16(f32x16 v) {
  float a0 = fmaxf(v[0], v[1]),  a1 = fmaxf(v[2], v[3]);
  float a2 = fmaxf(v[4], v[5]),  a3 = fmaxf(v[6], v[7]);
  float a4 = fmaxf(v[8], v[9]),  a5 = fmaxf(v[10], v[11]);
  float a6 = fmaxf(v[12], v[13]), a7 = fmaxf(v[14], v[15]);
  float b0 = fmaxf(a0, a1), b1 = fmaxf(a2, a3), b2 = fmaxf(a4, a5), b3 = fmaxf(a6, a7);
  return fmaxf(fmaxf(b0, b1), fmaxf(b2, b3));
}

// ---------------- prep kernels ----------------

__global__ void tab_kernel(const float* __restrict__ freqs, float2* __restrict__ tab) {
  int idx = blockIdx.x * blockDim.x + threadIdx.x;
  if (idx >= T_ * (D_/2)) return;
  int t = idx >> 7;
  int i = idx & 127;
  float ph = (float)t * freqs[2*i];
  ph -= floorf(ph);
  float ang = ph * 6.283185307179586f;
  tab[idx] = make_float2(cosf(ang), sinf(ang));
}

// KR[row][d] = rope(Q)[row][d] * KSCALE  (bf16). row = bh*T + t.
__global__ __launch_bounds__(256) void kr_kernel(const float* __restrict__ Q,
                                                 const float2* __restrict__ tab,
                                                 ushort_t* __restrict__ KR) {
  int row = blockIdx.x * 8 + (threadIdx.x >> 5);
  int d8  = threadIdx.x & 31;
  int t = row & (T_ - 1);
  const float* src = Q + (size_t)row * D_ + d8 * 8;
  float4 x0 = *(const float4*)src;
  float4 x1 = *(const float4*)(src + 4);
  const float2* tr = tab + t * (D_/2) + d8 * 4;
  float2 c0 = tr[0], c1 = tr[1], c2 = tr[2], c3 = tr[3];
  bf16x8 f;
  f[0] = f2bf((x0.x * c0.x - x0.y * c0.y) * KSCALE);
  f[1] = f2bf((x0.y * c0.x + x0.x * c0.y) * KSCALE);
  f[2] = f2bf((x0.z * c1.x - x0.w * c1.y) * KSCALE);
  f[3] = f2bf((x0.w * c1.x + x0.z * c1.y) * KSCALE);
  f[4] = f2bf((x1.x * c2.x - x1.y * c2.y) * KSCALE);
  f[5] = f2bf((x1.y * c2.x + x1.x * c2.y) * KSCALE);
  f[6] = f2bf((x1.z * c3.x - x1.w * c3.y) * KSCALE);
  f[7] = f2bf((x1.w * c3.x + x1.z * c3.y) * KSCALE);
  *(bf16x8*)(KR + (size_t)row * D_ + d8 * 8) = f;
}

// VT[bh][d][t] = bf16(V[bh][t][d]) via 64x64 LDS tile transpose
__global__ __launch_bounds__(256) void vt_kernel(const float* __restrict__ V,
                                                 ushort_t* __restrict__ VT) {
  int blk = blockIdx.x;
  int d64 = blk & 3, t64 = (blk >> 2) & 15, bh = blk >> 6;
  __shared__ ushort_t st[64][66];
  {
    int t = threadIdx.x >> 2, j = threadIdx.x & 3;
    const float* src = V + ((size_t)bh * T_ + t64 * 64 + t) * D_ + d64 * 64 + j * 16;
#pragma unroll
    for (int q2 = 0; q2 < 4; ++q2) {
      float4 x = *(const float4*)(src + q2 * 4);
      st[t][j*16 + q2*4 + 0] = (ushort_t)f2bf(x.x);
      st[t][j*16 + q2*4 + 1] = (ushort_t)f2bf(x.y);
      st[t][j*16 + q2*4 + 2] = (ushort_t)f2bf(x.z);
      st[t][j*16 + q2*4 + 3] = (ushort_t)f2bf(x.w);
    }
  }
  __syncthreads();
  {
    int d = threadIdx.x >> 2, tq = threadIdx.x & 3;
    bf16x8 a_, b_;
#pragma unroll
    for (int i = 0; i < 8; ++i) {
      a_[i] = (short)st[tq*16 + i][d];
      b_[i] = (short)st[tq*16 + 8 + i][d];
    }
    ushort_t* dst = VT + ((size_t)bh * D_ + d64*64 + d) * T_ + t64*64 + tq*16;
    *(bf16x8*)dst = a_;
    *(bf16x8*)(dst + 8) = b_;
  }
}

// ---------------- attention kernel ----------------
// attn3-proven iteration (single __syncthreads at end; its implicit vmcnt(0)
// drain completes the t+1 staging issued at iteration start — overlap with
// compute(t) is already achieved). 8 waves / 512 threads / QBLK=256.
// LDS layouts (16B-chunk XOR swizzles, conflict-free per 8-lane clock group):
//   K tile [32 s][256 d]: stored chunk (s, c) holds data chunk (s, c ^ (s&7))
//   V tile [256 d][32 s]: stored chunk (d, c) holds data chunk (d, c ^ ((d>>1)&3))
#define ATTN_ITER(TT, KC, VC, KN, VN)                                          \
  {                                                                            \
    const int tt_ = (TT);                                                      \
    if (tt_ + 1 < NKV) {                                                       \
      const ushort_t* Ks_ = KRb + (size_t)(tt_ + 1) * (KVB * D_);              \
      const ushort_t* Vs_ = VTb + (size_t)(tt_ + 1) * KVB;                     \
      _Pragma("unroll")                                                        \
      for (int i = 0; i < 2; ++i) {                                            \
        gload16(Ks_ + koff[i], &KN[((i * 8 + wv) * 64) * 8]);                  \
        gload16(Vs_ + voff[i], &VN[((i * 8 + wv) * 64) * 8]);                  \
      }                                                                        \
    }                                                                          \
    f32x16 s0_ = Z16, s1_ = Z16, s2_ = Z16, s3_ = Z16;                         \
    __builtin_amdgcn_s_setprio(1);                                             \
    _Pragma("unroll")                                                          \
    for (int m = 0; m < 16; m += 4) {                                          \
      bf16x8 kfa_ = *(const bf16x8*)&KC[lo * 256 + (((2*m + hi)     ^ (lo & 7)) * 8)]; \
      bf16x8 kfb_ = *(const bf16x8*)&KC[lo * 256 + (((2*m + 2 + hi) ^ (lo & 7)) * 8)]; \
      bf16x8 kfc_ = *(const bf16x8*)&KC[lo * 256 + (((2*m + 4 + hi) ^ (lo & 7)) * 8)]; \
      bf16x8 kfd_ = *(const bf16x8*)&KC[lo * 256 + (((2*m + 6 + hi) ^ (lo & 7)) * 8)]; \
      s0_ = __builtin_amdgcn_mfma_f32_32x32x16_bf16(kfa_, qf[m],   s0_, 0, 0, 0); \
      s1_ = __builtin_amdgcn_mfma_f32_32x32x16_bf16(kfb_, qf[m+1], s1_, 0, 0, 0); \
      s2_ = __builtin_amdgcn_mfma_f32_32x32x16_bf16(kfc_, qf[m+2], s2_, 0, 0, 0); \
      s3_ = __builtin_amdgcn_mfma_f32_32x32x16_bf16(kfd_, qf[m+3], s3_, 0, 0, 0); \
    }                                                                          \
    __builtin_amdgcn_s_setprio(0);                                             \
    f32x16 sacc_ = (s0_ + s1_) + (s2_ + s3_);                                  \
    float pm_ = hmax16(sacc_);                                                 \
    pm_ = fmaxf(pm_, __shfl_xor(pm_, 32));                                     \
    if (!__all(pm_ <= mR + 8.0f)) {                                            \
      float nm_ = fmaxf(mR, pm_);                                              \
      float corr_ = exp2f(mR - nm_);                                           \
      mR = nm_;                                                                \
      lR *= corr_;                                                             \
      if (hi == 0) bcw[lo] = corr_;                                            \
      asm volatile("s_waitcnt lgkmcnt(0)" ::: "memory");                       \
      _Pragma("unroll")                                                        \
      for (int g2 = 0; g2 < 4; ++g2) {                                         \
        float4 cr_ = *(const float4*)&bcw[g2 * 8 + hi * 4];                    \
        _Pragma("unroll")                                                      \
        for (int dt = 0; dt < 8; ++dt) {                                       \
          oacc[dt][g2*4 + 0] *= cr_.x;                                         \
          oacc[dt][g2*4 + 1] *= cr_.y;                                         \
          oacc[dt][g2*4 + 2] *= cr_.z;                                         \
          oacc[dt][g2*4 + 3] *= cr_.w;                                         \
        }                                                                      \
      }                                                                        \
    }                                                                          \
    float p_[16];                                                              \
    _Pragma("unroll")                                                          \
    for (int r = 0; r < 16; ++r) p_[r] = exp2f(sacc_[r] - mR);                 \
    float ps_ = (((p_[0]+p_[1]) + (p_[2]+p_[3])) + ((p_[4]+p_[5]) + (p_[6]+p_[7]))) \
              + (((p_[8]+p_[9]) + (p_[10]+p_[11])) + ((p_[12]+p_[13]) + (p_[14]+p_[15]))); \
    ps_ += __shfl_xor(ps_, 32);                                                \
    lR += ps_;                                                                 \
    unsigned int c00_, c01_, c10_, c11_, c20_, c21_, c30_, c31_;               \
    asm("v_cvt_pk_bf16_f32 %0, %1, %2" : "=v"(c00_) : "v"(p_[0]),  "v"(p_[1])); \
    asm("v_cvt_pk_bf16_f32 %0, %1, %2" : "=v"(c01_) : "v"(p_[2]),  "v"(p_[3])); \
    asm("v_cvt_pk_bf16_f32 %0, %1, %2" : "=v"(c10_) : "v"(p_[4]),  "v"(p_[5])); \
    asm("v_cvt_pk_bf16_f32 %0, %1, %2" : "=v"(c11_) : "v"(p_[6]),  "v"(p_[7])); \
    asm("v_cvt_pk_bf16_f32 %0, %1, %2" : "=v"(c20_) : "v"(p_[8]),  "v"(p_[9])); \
    asm("v_cvt_pk_bf16_f32 %0, %1, %2" : "=v"(c21_) : "v"(p_[10]), "v"(p_[11])); \
    asm("v_cvt_pk_bf16_f32 %0, %1, %2" : "=v"(c30_) : "v"(p_[12]), "v"(p_[13])); \
    asm("v_cvt_pk_bf16_f32 %0, %1, %2" : "=v"(c31_) : "v"(p_[14]), "v"(p_[15])); \
    asm("v_permlane32_swap_b32 %0, %1" : "+v"(c00_), "+v"(c10_));              \
    asm("v_permlane32_swap_b32 %0, %1" : "+v"(c01_), "+v"(c11_));              \
    asm("v_permlane32_swap_b32 %0, %1" : "+v"(c20_), "+v"(c30_));              \
    asm("v_permlane32_swap_b32 %0, %1" : "+v"(c21_), "+v"(c31_));              \
    bf16x8 pA_, pB_;                                                           \
    {                                                                          \
      union { unsigned int u[4]; bf16x8 v; } tA_, tB_;                         \
      tA_.u[0] = c00_; tA_.u[1] = c01_; tA_.u[2] = c10_; tA_.u[3] = c11_;      \
      tB_.u[0] = c20_; tB_.u[1] = c21_; tB_.u[2] = c30_; tB_.u[3] = c31_;      \
      pA_ = tA_.v; pB_ = tB_.v;                                                \
    }                                                                          \
    __builtin_amdgcn_s_setprio(1);                                             \
    _Pragma("unroll")                                                          \
    for (int dt = 0; dt < 8; ++dt) {                                           \
      bf16x8 vf0_ = *(const bf16x8*)&VC[(dt*32 + lo) * 32 + ((hi ^ vswz) * 8)]; \
      oacc[dt] = __builtin_amdgcn_mfma_f32_32x32x16_bf16(pA_, vf0_, oacc[dt], 0, 0, 0); \
      bf16x8 vf1_ = *(const bf16x8*)&VC[(dt*32 + lo) * 32 + (((2 + hi) ^ vswz) * 8)]; \
      oacc[dt] = __builtin_amdgcn_mfma_f32_32x32x16_bf16(pB_, vf1_, oacc[dt], 0, 0, 0); \
    }                                                                          \
    __builtin_amdgcn_s_setprio(0);                                             \
    __syncthreads();                                                           \
  }

__global__ __launch_bounds__(512, 2)
void attn6(const ushort_t* __restrict__ KR, const ushort_t* __restrict__ VT,
           float* __restrict__ O) {
  int bid = blockIdx.x;
  int swz = (bid & 7) * (NBLK / 8) + (bid >> 3);   // bijective: 384 % 8 == 0
  int qb = swz & (NQB - 1);
  int bh = swz >> 2;

  const ushort_t* __restrict__ KRb = KR + (size_t)bh * T_ * D_;
  const ushort_t* __restrict__ VTb = VT + (size_t)bh * D_ * T_;
  float* __restrict__ Ob = O + (size_t)bh * T_ * D_;

  const int tid = threadIdx.x, lane = tid & 63, wv = tid >> 6;  // wv 0..7
  const int lo = lane & 31, hi = lane >> 5;
  const int vswz = (lo >> 1) & 3;
  const int q0 = qb * QBLK + wv * QW;

  __shared__ __align__(16) ushort_t Kb0[KVB * D_];
  __shared__ __align__(16) ushort_t Kb1[KVB * D_];
  __shared__ __align__(16) ushort_t Vb0[D_ * KVB];
  __shared__ __align__(16) ushort_t Vb1[D_ * KVB];
  __shared__ __align__(16) float bc[8][32];

  float* bcw = bc[wv];

  // stage address maps (per lane, constant across tiles; inverse-swizzled source)
  // 1024 chunks per tile, 512 threads -> 2 chunks each
  int koff[2], voff[2];
#pragma unroll
  for (int i = 0; i < 2; ++i) {
    int ch = (i * 8 + wv) * 64 + lane;
    int r = ch >> 5, c = ch & 31;
    koff[i] = r * 256 + ((c ^ (r & 7)) * 8);
    int d = ch >> 2, c2 = ch & 3;
    voff[i] = d * 1024 + ((c2 ^ ((d >> 1) & 3)) * 8);
  }

  // resident Q fragments (rows of KR; KSCALE pre-applied on both operands)
  bf16x8 qf[16];
  {
    const ushort_t* qrow = KRb + (size_t)(q0 + lo) * D_ + hi * 8;
#pragma unroll
    for (int m = 0; m < 16; ++m) qf[m] = *(const bf16x8*)(qrow + m * 16);
  }

  f32x16 oacc[8];
#pragma unroll
  for (int dt = 0; dt < 8; ++dt) oacc[dt] = Z16;
  float mR = -1e30f, lR = 0.0f;

  // prologue: stage tile 0 into buffer 0
#pragma unroll
  for (int i = 0; i < 2; ++i) {
    gload16(KRb + koff[i], &Kb0[((i * 8 + wv) * 64) * 8]);
    gload16(VTb + voff[i], &Vb0[((i * 8 + wv) * 64) * 8]);
  }
  __syncthreads();

  for (int t = 0; t < NKV; t += 2) {
    ATTN_ITER(t,     Kb0, Vb0, Kb1, Vb1);
    ATTN_ITER(t + 1, Kb1, Vb1, Kb0, Vb0);
  }

  // epilogue: broadcast 1/l per q-row, normalize, store
  if (hi == 0) bcw[lo] = 1.0f / lR;
  asm volatile("s_waitcnt lgkmcnt(0)" ::: "memory");
#pragma unroll
  for (int g2 = 0; g2 < 4; ++g2) {
    float4 il = *(const float4*)&bcw[g2 * 8 + hi * 4];
#pragma unroll
    for (int j = 0; j < 4; ++j) {
      int r = g2 * 4 + j;
      int qr = j + 8 * g2 + 4 * hi;
      float sc = (j == 0) ? il.x : (j == 1) ? il.y : (j == 2) ? il.z : il.w;
#pragma unroll
      for (int dt = 0; dt < 8; ++dt)
        Ob[(size_t)(q0 + qr) * D_ + dt * 32 + lo] = oacc[dt][r] * sc;
    }
  }
}

extern "C" void kernel_launch(void* const* d_in, const int* in_sizes, int n_in,
                              void* d_out, int out_size, void* d_ws, size_t ws_size,
                              hipStream_t stream) {
  const float* Q     = (const float*)d_in[0];
  const float* V     = (const float*)d_in[1];
  const float* freqs = (const float*)d_in[2];
  float* Out = (float*)d_out;

  float2* tab  = (float2*)d_ws;                                   // 1 MB
  ushort_t* KR = (ushort_t*)((char*)d_ws + (1 << 20));            // 48 MB
  ushort_t* VT = (ushort_t*)((char*)d_ws + (1 << 20) + (size_t)NBH * T_ * D_ * 2);  // 48 MB

  tab_kernel<<<(T_ * (D_/2) + 255) / 256, 256, 0, stream>>>(freqs, tab);
  kr_kernel<<<NBH * T_ / 8, 256, 0, stream>>>(Q, tab, KR);
  vt_kernel<<<NBH * 16 * 4, 256, 0, stream>>>(V, VT);
  attn6<<<NBLK, 512, 0, stream>>>(KR, VT, Out);
}

// Round 7
// 407.243 us; speedup vs baseline: 1.3074x; 1.2425x over previous
//
#include <hip/hip_runtime.h>
#include <hip/hip_bf16.h>
#include <stdint.h>

#define B_ 8
#define NH_ 12
#define NBH (B_*NH_)       // 96
#define T_ 1024
#define D_ 256
#define QBLK 128           // q rows per block (4 waves x 32)
#define QW 32              // q rows per wave
#define KVB 32             // kv tile
#define NKV (T_/KVB)       // 32
#define NQB (T_/QBLK)      // 8
#define NBLK (NBH*NQB)     // 768

typedef __attribute__((ext_vector_type(8))) short bf16x8;
typedef __attribute__((ext_vector_type(16))) float f32x16;
typedef unsigned short ushort_t;

#define Z16 ((f32x16){0,0,0,0,0,0,0,0,0,0,0,0,0,0,0,0})

// KR pre-scale: 0.25 * sqrt(log2(e)) so that (KR.KR) = (S/sqrt(256)) * log2(e)
#define KSCALE 0.30028060218f

__device__ __forceinline__ short f2bf(float x) {
  __hip_bfloat16 h = __float2bfloat16(x);
  return *reinterpret_cast<short*>(&h);
}
__device__ __forceinline__ void gload16(const ushort_t* g, ushort_t* l) {
  __builtin_amdgcn_global_load_lds(
      (const __attribute__((address_space(1))) uint32_t*)g,
      (__attribute__((address_space(3))) uint32_t*)l, 16, 0, 0);
}
__device__ __forceinline__ float hmax16(f32x16 v) {
  float a0 = fmaxf(v[0], v[1]),  a1 = fmaxf(v[2], v[3]);
  float a2 = fmaxf(v[4], v[5]),  a3 = fmaxf(v[6], v[7]);
  float a4 = fmaxf(v[8], v[9]),  a5 = fmaxf(v[10], v[11]);
  float a6 = fmaxf(v[12], v[13]), a7 = fmaxf(v[14], v[15]);
  float b0 = fmaxf(a0, a1), b1 = fmaxf(a2, a3), b2 = fmaxf(a4, a5), b3 = fmaxf(a6, a7);
  return fmaxf(fmaxf(b0, b1), fmaxf(b2, b3));
}

// ---------------- prep kernels ----------------

__global__ void tab_kernel(const float* __restrict__ freqs, float2* __restrict__ tab) {
  int idx = blockIdx.x * blockDim.x + threadIdx.x;
  if (idx >= T_ * (D_/2)) return;
  int t = idx >> 7;
  int i = idx & 127;
  float ph = (float)t * freqs[2*i];
  ph -= floorf(ph);
  float ang = ph * 6.283185307179586f;
  tab[idx] = make_float2(cosf(ang), sinf(ang));
}

// KR[row][d] = rope(Q)[row][d] * KSCALE  (bf16). row = bh*T + t.
__global__ __launch_bounds__(256) void kr_kernel(const float* __restrict__ Q,
                                                 const float2* __restrict__ tab,
                                                 ushort_t* __restrict__ KR) {
  int row = blockIdx.x * 8 + (threadIdx.x >> 5);
  int d8  = threadIdx.x & 31;
  int t = row & (T_ - 1);
  const float* src = Q + (size_t)row * D_ + d8 * 8;
  float4 x0 = *(const float4*)src;
  float4 x1 = *(const float4*)(src + 4);
  const float2* tr = tab + t * (D_/2) + d8 * 4;
  float2 c0 = tr[0], c1 = tr[1], c2 = tr[2], c3 = tr[3];
  bf16x8 f;
  f[0] = f2bf((x0.x * c0.x - x0.y * c0.y) * KSCALE);
  f[1] = f2bf((x0.y * c0.x + x0.x * c0.y) * KSCALE);
  f[2] = f2bf((x0.z * c1.x - x0.w * c1.y) * KSCALE);
  f[3] = f2bf((x0.w * c1.x + x0.z * c1.y) * KSCALE);
  f[4] = f2bf((x1.x * c2.x - x1.y * c2.y) * KSCALE);
  f[5] = f2bf((x1.y * c2.x + x1.x * c2.y) * KSCALE);
  f[6] = f2bf((x1.z * c3.x - x1.w * c3.y) * KSCALE);
  f[7] = f2bf((x1.w * c3.x + x1.z * c3.y) * KSCALE);
  *(bf16x8*)(KR + (size_t)row * D_ + d8 * 8) = f;
}

// VT[bh][d][t] = bf16(V[bh][t][d]) via 64x64 LDS tile transpose
__global__ __launch_bounds__(256) void vt_kernel(const float* __restrict__ V,
                                                 ushort_t* __restrict__ VT) {
  int blk = blockIdx.x;
  int d64 = blk & 3, t64 = (blk >> 2) & 15, bh = blk >> 6;
  __shared__ ushort_t st[64][66];
  {
    int t = threadIdx.x >> 2, j = threadIdx.x & 3;
    const float* src = V + ((size_t)bh * T_ + t64 * 64 + t) * D_ + d64 * 64 + j * 16;
#pragma unroll
    for (int q2 = 0; q2 < 4; ++q2) {
      float4 x = *(const float4*)(src + q2 * 4);
      st[t][j*16 + q2*4 + 0] = (ushort_t)f2bf(x.x);
      st[t][j*16 + q2*4 + 1] = (ushort_t)f2bf(x.y);
      st[t][j*16 + q2*4 + 2] = (ushort_t)f2bf(x.z);
      st[t][j*16 + q2*4 + 3] = (ushort_t)f2bf(x.w);
    }
  }
  __syncthreads();
  {
    int d = threadIdx.x >> 2, tq = threadIdx.x & 3;
    bf16x8 a_, b_;
#pragma unroll
    for (int i = 0; i < 8; ++i) {
      a_[i] = (short)st[tq*16 + i][d];
      b_[i] = (short)st[tq*16 + 8 + i][d];
    }
    ushort_t* dst = VT + ((size_t)bh * D_ + d64*64 + d) * T_ + t64*64 + tq*16;
    *(bf16x8*)dst = a_;
    *(bf16x8*)(dst + 8) = b_;
  }
}

// ---------------- attention kernel ----------------
// r3-proven iteration; register diet: SINGLE QK accumulator chain (s0_ is both
// chain and S-tile; no sacc copy), softmax p computed in 4-element groups.
// Target: total VGPR+AGPR <= 256/wave so launch_bounds(256,2) actually fits
// 2 waves/SIMD (r3 was ~288 -> 1 wave/SIMD, zero latency hiding).
#define ATTN_ITER(TT, KC, VC, KN, VN)                                          \
  {                                                                            \
    const int tt_ = (TT);                                                      \
    if (tt_ + 1 < NKV) {                                                       \
      const ushort_t* Ks_ = KRb + (size_t)(tt_ + 1) * (KVB * D_);              \
      const ushort_t* Vs_ = VTb + (size_t)(tt_ + 1) * KVB;                     \
      _Pragma("unroll")                                                        \
      for (int i = 0; i < 4; ++i) {                                            \
        gload16(Ks_ + koff[i], &KN[((i * 4 + wv) * 64) * 8]);                  \
        gload16(Vs_ + voff[i], &VN[((i * 4 + wv) * 64) * 8]);                  \
      }                                                                        \
    }                                                                          \
    f32x16 s0_ = Z16;                                                          \
    __builtin_amdgcn_s_setprio(1);                                             \
    _Pragma("unroll")                                                          \
    for (int m = 0; m < 16; ++m) {                                             \
      bf16x8 kfa_ = *(const bf16x8*)&KC[lo * 256 + (((2*m + hi) ^ (lo & 7)) * 8)]; \
      s0_ = __builtin_amdgcn_mfma_f32_32x32x16_bf16(kfa_, qf[m], s0_, 0, 0, 0);\
    }                                                                          \
    __builtin_amdgcn_s_setprio(0);                                             \
    float pm_ = hmax16(s0_);                                                   \
    pm_ = fmaxf(pm_, __shfl_xor(pm_, 32));                                     \
    if (!__all(pm_ <= mR + 8.0f)) {                                            \
      float nm_ = fmaxf(mR, pm_);                                              \
      float corr_ = exp2f(mR - nm_);                                           \
      mR = nm_;                                                                \
      lR *= corr_;                                                             \
      if (hi == 0) bcw[lo] = corr_;                                            \
      asm volatile("s_waitcnt lgkmcnt(0)" ::: "memory");                       \
      _Pragma("unroll")                                                        \
      for (int g2 = 0; g2 < 4; ++g2) {                                         \
        float4 cr_ = *(const float4*)&bcw[g2 * 8 + hi * 4];                    \
        _Pragma("unroll")                                                      \
        for (int dt = 0; dt < 8; ++dt) {                                       \
          oacc[dt][g2*4 + 0] *= cr_.x;                                         \
          oacc[dt][g2*4 + 1] *= cr_.y;                                         \
          oacc[dt][g2*4 + 2] *= cr_.z;                                         \
          oacc[dt][g2*4 + 3] *= cr_.w;                                         \
        }                                                                      \
      }                                                                        \
    }                                                                          \
    unsigned int c_[8];                                                        \
    float ps_ = 0.0f;                                                          \
    _Pragma("unroll")                                                          \
    for (int g3 = 0; g3 < 4; ++g3) {                                           \
      float pa_ = exp2f(s0_[4*g3 + 0] - mR);                                   \
      float pb_ = exp2f(s0_[4*g3 + 1] - mR);                                   \
      float pc_ = exp2f(s0_[4*g3 + 2] - mR);                                   \
      float pd_ = exp2f(s0_[4*g3 + 3] - mR);                                   \
      ps_ += (pa_ + pb_) + (pc_ + pd_);                                        \
      asm("v_cvt_pk_bf16_f32 %0, %1, %2" : "=v"(c_[2*g3])   : "v"(pa_), "v"(pb_)); \
      asm("v_cvt_pk_bf16_f32 %0, %1, %2" : "=v"(c_[2*g3+1]) : "v"(pc_), "v"(pd_)); \
    }                                                                          \
    ps_ += __shfl_xor(ps_, 32);                                                \
    lR += ps_;                                                                 \
    asm("v_permlane32_swap_b32 %0, %1" : "+v"(c_[0]), "+v"(c_[2]));            \
    asm("v_permlane32_swap_b32 %0, %1" : "+v"(c_[1]), "+v"(c_[3]));            \
    asm("v_permlane32_swap_b32 %0, %1" : "+v"(c_[4]), "+v"(c_[6]));            \
    asm("v_permlane32_swap_b32 %0, %1" : "+v"(c_[5]), "+v"(c_[7]));            \
    bf16x8 pA_, pB_;                                                           \
    {                                                                          \
      union { unsigned int u[4]; bf16x8 v; } tA_, tB_;                         \
      tA_.u[0] = c_[0]; tA_.u[1] = c_[1]; tA_.u[2] = c_[2]; tA_.u[3] = c_[3];  \
      tB_.u[0] = c_[4]; tB_.u[1] = c_[5]; tB_.u[2] = c_[6]; tB_.u[3] = c_[7];  \
      pA_ = tA_.v; pB_ = tB_.v;                                                \
    }                                                                          \
    __builtin_amdgcn_s_setprio(1);                                             \
    _Pragma("unroll")                                                          \
    for (int dt = 0; dt < 8; ++dt) {                                           \
      bf16x8 vf0_ = *(const bf16x8*)&VC[(dt*32 + lo) * 32 + ((hi ^ vswz) * 8)]; \
      oacc[dt] = __builtin_amdgcn_mfma_f32_32x32x16_bf16(pA_, vf0_, oacc[dt], 0, 0, 0); \
      bf16x8 vf1_ = *(const bf16x8*)&VC[(dt*32 + lo) * 32 + (((2 + hi) ^ vswz) * 8)]; \
      oacc[dt] = __builtin_amdgcn_mfma_f32_32x32x16_bf16(pB_, vf1_, oacc[dt], 0, 0, 0); \
    }                                                                          \
    __builtin_amdgcn_s_setprio(0);                                             \
    __syncthreads();                                                           \
  }

__global__ __launch_bounds__(256, 2)
void attn7(const ushort_t* __restrict__ KR, const ushort_t* __restrict__ VT,
           float* __restrict__ O) {
  int bid = blockIdx.x;
  int swz = (bid & 7) * (NBLK / 8) + (bid >> 3);   // bijective: 768 % 8 == 0
  int qb = swz & (NQB - 1);
  int bh = swz >> 3;

  const ushort_t* __restrict__ KRb = KR + (size_t)bh * T_ * D_;
  const ushort_t* __restrict__ VTb = VT + (size_t)bh * D_ * T_;
  float* __restrict__ Ob = O + (size_t)bh * T_ * D_;

  const int tid = threadIdx.x, lane = tid & 63, wv = tid >> 6;
  const int lo = lane & 31, hi = lane >> 5;
  const int vswz = (lo >> 1) & 3;
  const int q0 = qb * QBLK + wv * QW;

  __shared__ __align__(16) ushort_t Kb0[KVB * D_];
  __shared__ __align__(16) ushort_t Kb1[KVB * D_];
  __shared__ __align__(16) ushort_t Vb0[D_ * KVB];
  __shared__ __align__(16) ushort_t Vb1[D_ * KVB];
  __shared__ __align__(16) float bc[4][32];

  float* bcw = bc[wv];

  // stage address maps (per lane, constant across tiles; inverse-swizzled source)
  int koff[4], voff[4];
#pragma unroll
  for (int i = 0; i < 4; ++i) {
    int ch = (i * 4 + wv) * 64 + lane;
    int r = ch >> 5, c = ch & 31;
    koff[i] = r * 256 + ((c ^ (r & 7)) * 8);
    int d = ch >> 2, c2 = ch & 3;
    voff[i] = d * 1024 + ((c2 ^ ((d >> 1) & 3)) * 8);
  }

  // resident Q fragments (rows of KR; KSCALE pre-applied on both operands)
  bf16x8 qf[16];
  {
    const ushort_t* qrow = KRb + (size_t)(q0 + lo) * D_ + hi * 8;
#pragma unroll
    for (int m = 0; m < 16; ++m) qf[m] = *(const bf16x8*)(qrow + m * 16);
  }

  f32x16 oacc[8];
#pragma unroll
  for (int dt = 0; dt < 8; ++dt) oacc[dt] = Z16;
  float mR = -1e30f, lR = 0.0f;

  // prologue: stage tile 0 into buffer 0
#pragma unroll
  for (int i = 0; i < 4; ++i) {
    gload16(KRb + koff[i], &Kb0[((i * 4 + wv) * 64) * 8]);
    gload16(VTb + voff[i], &Vb0[((i * 4 + wv) * 64) * 8]);
  }
  __syncthreads();

  for (int t = 0; t < NKV; t += 2) {
    ATTN_ITER(t,     Kb0, Vb0, Kb1, Vb1);
    ATTN_ITER(t + 1, Kb1, Vb1, Kb0, Vb0);
  }

  // epilogue: broadcast 1/l per q-row, normalize, store
  if (hi == 0) bcw[lo] = 1.0f / lR;
  asm volatile("s_waitcnt lgkmcnt(0)" ::: "memory");
#pragma unroll
  for (int g2 = 0; g2 < 4; ++g2) {
    float4 il = *(const float4*)&bcw[g2 * 8 + hi * 4];
#pragma unroll
    for (int j = 0; j < 4; ++j) {
      int r = g2 * 4 + j;
      int qr = j + 8 * g2 + 4 * hi;
      float sc = (j == 0) ? il.x : (j == 1) ? il.y : (j == 2) ? il.z : il.w;
#pragma unroll
      for (int dt = 0; dt < 8; ++dt)
        Ob[(size_t)(q0 + qr) * D_ + dt * 32 + lo] = oacc[dt][r] * sc;
    }
  }
}

extern "C" void kernel_launch(void* const* d_in, const int* in_sizes, int n_in,
                              void* d_out, int out_size, void* d_ws, size_t ws_size,
                              hipStream_t stream) {
  const float* Q     = (const float*)d_in[0];
  const float* V     = (const float*)d_in[1];
  const float* freqs = (const float*)d_in[2];
  float* Out = (float*)d_out;

  float2* tab  = (float2*)d_ws;                                   // 1 MB
  ushort_t* KR = (ushort_t*)((char*)d_ws + (1 << 20));            // 48 MB
  ushort_t* VT = (ushort_t*)((char*)d_ws + (1 << 20) + (size_t)NBH * T_ * D_ * 2);  // 48 MB

  tab_kernel<<<(T_ * (D_/2) + 255) / 256, 256, 0, stream>>>(freqs, tab);
  kr_kernel<<<NBH * T_ / 8, 256, 0, stream>>>(Q, tab, KR);
  vt_kernel<<<NBH * 16 * 4, 256, 0, stream>>>(V, VT);
  attn7<<<NBLK, 256, 0, stream>>>(KR, VT, Out);
}

// Round 8
// 262.014 us; speedup vs baseline: 2.0321x; 1.5543x over previous
//
#include <hip/hip_runtime.h>
#include <hip/hip_bf16.h>
#include <stdint.h>

#define B_ 8
#define NH_ 12
#define NBH (B_*NH_)       // 96
#define T_ 1024
#define D_ 256
#define GRP 48             // heads per group (P buffer = GRP*2MB = 96MB)
#define NG (NBH/GRP)       // 2
#define G1BLK (GRP*8*8)    // 3072 gemm1 blocks per group
#define G2BLK (GRP*8*2)    // 768  gemm2 blocks per group

typedef __attribute__((ext_vector_type(8))) short bf16x8;
typedef __attribute__((ext_vector_type(16))) float f32x16;
typedef unsigned short ushort_t;

#define Z16 ((f32x16){0,0,0,0,0,0,0,0,0,0,0,0,0,0,0,0})

// KR pre-scale: 0.25 * sqrt(log2(e)) so that (KR.KR^T) = (S/sqrt(256)) * log2(e)
#define KSCALE 0.30028060218f

__device__ __forceinline__ short f2bf(float x) {
  __hip_bfloat16 h = __float2bfloat16(x);
  return *reinterpret_cast<short*>(&h);
}
__device__ __forceinline__ float bf2f(short x) {
  unsigned int u = ((unsigned int)(unsigned short)x) << 16;
  return __uint_as_float(u);
}
__device__ __forceinline__ void gload16(const ushort_t* g, ushort_t* l) {
  __builtin_amdgcn_global_load_lds(
      (const __attribute__((address_space(1))) uint32_t*)g,
      (__attribute__((address_space(3))) uint32_t*)l, 16, 0, 0);
}

// ---------------- prep kernels (unchanged, proven) ----------------

__global__ void tab_kernel(const float* __restrict__ freqs, float2* __restrict__ tab) {
  int idx = blockIdx.x * blockDim.x + threadIdx.x;
  if (idx >= T_ * (D_/2)) return;
  int t = idx >> 7;
  int i = idx & 127;
  float ph = (float)t * freqs[2*i];
  ph -= floorf(ph);
  float ang = ph * 6.283185307179586f;
  tab[idx] = make_float2(cosf(ang), sinf(ang));
}

__global__ __launch_bounds__(256) void kr_kernel(const float* __restrict__ Q,
                                                 const float2* __restrict__ tab,
                                                 ushort_t* __restrict__ KR) {
  int row = blockIdx.x * 8 + (threadIdx.x >> 5);
  int d8  = threadIdx.x & 31;
  int t = row & (T_ - 1);
  const float* src = Q + (size_t)row * D_ + d8 * 8;
  float4 x0 = *(const float4*)src;
  float4 x1 = *(const float4*)(src + 4);
  const float2* tr = tab + t * (D_/2) + d8 * 4;
  float2 c0 = tr[0], c1 = tr[1], c2 = tr[2], c3 = tr[3];
  bf16x8 f;
  f[0] = f2bf((x0.x * c0.x - x0.y * c0.y) * KSCALE);
  f[1] = f2bf((x0.y * c0.x + x0.x * c0.y) * KSCALE);
  f[2] = f2bf((x0.z * c1.x - x0.w * c1.y) * KSCALE);
  f[3] = f2bf((x0.w * c1.x + x0.z * c1.y) * KSCALE);
  f[4] = f2bf((x1.x * c2.x - x1.y * c2.y) * KSCALE);
  f[5] = f2bf((x1.y * c2.x + x1.x * c2.y) * KSCALE);
  f[6] = f2bf((x1.z * c3.x - x1.w * c3.y) * KSCALE);
  f[7] = f2bf((x1.w * c3.x + x1.z * c3.y) * KSCALE);
  *(bf16x8*)(KR + (size_t)row * D_ + d8 * 8) = f;
}

__global__ __launch_bounds__(256) void vt_kernel(const float* __restrict__ V,
                                                 ushort_t* __restrict__ VT) {
  int blk = blockIdx.x;
  int d64 = blk & 3, t64 = (blk >> 2) & 15, bh = blk >> 6;
  __shared__ ushort_t st[64][66];
  {
    int t = threadIdx.x >> 2, j = threadIdx.x & 3;
    const float* src = V + ((size_t)bh * T_ + t64 * 64 + t) * D_ + d64 * 64 + j * 16;
#pragma unroll
    for (int q2 = 0; q2 < 4; ++q2) {
      float4 x = *(const float4*)(src + q2 * 4);
      st[t][j*16 + q2*4 + 0] = (ushort_t)f2bf(x.x);
      st[t][j*16 + q2*4 + 1] = (ushort_t)f2bf(x.y);
      st[t][j*16 + q2*4 + 2] = (ushort_t)f2bf(x.z);
      st[t][j*16 + q2*4 + 3] = (ushort_t)f2bf(x.w);
    }
  }
  __syncthreads();
  {
    int d = threadIdx.x >> 2, tq = threadIdx.x & 3;
    bf16x8 a_, b_;
#pragma unroll
    for (int i = 0; i < 8; ++i) {
      a_[i] = (short)st[tq*16 + i][d];
      b_[i] = (short)st[tq*16 + 8 + i][d];
    }
    ushort_t* dst = VT + ((size_t)bh * D_ + d64*64 + d) * T_ + t64*64 + tq*16;
    *(bf16x8*)dst = a_;
    *(bf16x8*)(dst + 8) = b_;
  }
}

// ---------------- GEMM1: P = exp2(KR . KR^T)  (per head) ----------------
// Block = 128t x 128s, 4 waves (wave wv owns t-rows 32wv..+32), K=256 in 4 steps
// of BK=64. LDS tiles [128 rows][8 chunks of 16B], chunk swizzle c ^= (r&7)
// (conflict-free per 8-lane clock group; source pre-swizzled for gload16).
// MFMA convention (verified r1/r3): acc = mfma(A,B): col(lane&31) <-> B rows,
// crow(r,hi) = (r&3)+8(r>>2)+4hi <-> A rows.
__global__ __launch_bounds__(256, 4)
void gemm1_kernel(const ushort_t* __restrict__ KRg, ushort_t* __restrict__ P) {
  int bid = blockIdx.x;
  int swz = (bid & 7) * (G1BLK / 8) + (bid >> 3);   // bijective: 3072 % 8 == 0
  int si = swz & 7;
  int ti = (swz >> 3) & 7;
  int h  = swz >> 6;                                // 0..GRP-1

  const ushort_t* __restrict__ Kh = KRg + (size_t)h * (T_ * D_);
  ushort_t* __restrict__ Ph = P + (size_t)h * (T_ * T_);

  const int tid = threadIdx.x, lane = tid & 63, wv = tid >> 6;
  const int lo = lane & 31, hi = lane >> 5;

  __shared__ __align__(16) ushort_t At[128 * 64];   // t-rows tile
  __shared__ __align__(16) ushort_t Bt[128 * 64];   // s-rows tile

  f32x16 acc[4];
#pragma unroll
  for (int j = 0; j < 4; ++j) acc[j] = Z16;

  const ushort_t* Abase = Kh + (size_t)ti * 128 * D_;
  const ushort_t* Bbase = Kh + (size_t)si * 128 * D_;

  for (int ks = 0; ks < 4; ++ks) {
    int k0 = ks * 64;
    __syncthreads();                 // WAR: previous compute done
#pragma unroll
    for (int i = 0; i < 4; ++i) {
      int d = tid + i * 256;         // chunk index 0..1023
      int r = d >> 3, c = d & 7;
      int srcoff = r * D_ + k0 + ((c ^ (r & 7)) * 8);
      gload16(Abase + srcoff, &At[d * 8]);
      gload16(Bbase + srcoff, &Bt[d * 8]);
    }
    __syncthreads();                 // RAW (includes vmcnt drain)
    __builtin_amdgcn_s_setprio(1);
#pragma unroll
    for (int kk = 0; kk < 4; ++kk) {
      int ra = 32 * wv + lo;
      bf16x8 af = *(const bf16x8*)&At[ra * 64 + (((2*kk + hi) ^ (ra & 7)) * 8)];
#pragma unroll
      for (int j = 0; j < 4; ++j) {
        int rb = 32 * j + lo;
        bf16x8 bf_ = *(const bf16x8*)&Bt[rb * 64 + (((2*kk + hi) ^ (rb & 7)) * 8)];
        acc[j] = __builtin_amdgcn_mfma_f32_32x32x16_bf16(af, bf_, acc[j], 0, 0, 0);
      }
    }
    __builtin_amdgcn_s_setprio(0);
  }

  // epilogue: P[t][s] = bf16(exp2(acc));  32 lanes x 2B contiguous per (j,r)
#pragma unroll
  for (int j = 0; j < 4; ++j) {
#pragma unroll
    for (int r = 0; r < 16; ++r) {
      int t = ti * 128 + 32 * wv + ((r & 3) + 8 * (r >> 2) + 4 * hi);
      int s = si * 128 + 32 * j + lo;
      Ph[(size_t)t * T_ + s] = (ushort_t)f2bf(exp2f(acc[j][r]));
    }
  }
}

// ---------------- GEMM2: O = (P . V) / rowsum(P)  (per head) ----------------
// Block = 128t x 128d, K=1024 in 16 steps of BK=64. A = P rows(t), B = VT rows(d).
// l[t] accumulated from the same bf16 P fragments the MFMA consumes.
__global__ __launch_bounds__(256, 4)
void gemm2_kernel(const ushort_t* __restrict__ P, const ushort_t* __restrict__ VTg,
                  float* __restrict__ Og) {
  int bid = blockIdx.x;
  int swz = (bid & 7) * (G2BLK / 8) + (bid >> 3);   // bijective: 768 % 8 == 0
  int di = swz & 1;
  int ti = (swz >> 1) & 7;
  int h  = swz >> 4;                                // 0..GRP-1

  const ushort_t* __restrict__ Ph = P + (size_t)h * (T_ * T_);
  const ushort_t* __restrict__ Vh = VTg + (size_t)h * (D_ * T_);
  float* __restrict__ Oh = Og + (size_t)h * (T_ * D_);

  const int tid = threadIdx.x, lane = tid & 63, wv = tid >> 6;
  const int lo = lane & 31, hi = lane >> 5;

  __shared__ __align__(16) ushort_t At[128 * 64];   // P t-rows tile
  __shared__ __align__(16) ushort_t Bt[128 * 64];   // VT d-rows tile
  __shared__ float lB[4][32];

  f32x16 acc[4];
#pragma unroll
  for (int j = 0; j < 4; ++j) acc[j] = Z16;
  float lsum = 0.0f;

  const ushort_t* Abase = Ph + (size_t)ti * 128 * T_;
  const ushort_t* Bbase = Vh + (size_t)di * 128 * T_;

  for (int ks = 0; ks < 16; ++ks) {
    int k0 = ks * 64;
    __syncthreads();
#pragma unroll
    for (int i = 0; i < 4; ++i) {
      int d = tid + i * 256;
      int r = d >> 3, c = d & 7;
      int srcoff = r * T_ + k0 + ((c ^ (r & 7)) * 8);
      gload16(Abase + srcoff, &At[d * 8]);
      gload16(Bbase + srcoff, &Bt[d * 8]);
    }
    __syncthreads();
    __builtin_amdgcn_s_setprio(1);
#pragma unroll
    for (int kk = 0; kk < 4; ++kk) {
      int ra = 32 * wv + lo;
      bf16x8 pf = *(const bf16x8*)&At[ra * 64 + (((2*kk + hi) ^ (ra & 7)) * 8)];
      // accumulate row-sum of P (this lane's hi-half of row ra)
      float s01 = bf2f(pf[0]) + bf2f(pf[1]);
      float s23 = bf2f(pf[2]) + bf2f(pf[3]);
      float s45 = bf2f(pf[4]) + bf2f(pf[5]);
      float s67 = bf2f(pf[6]) + bf2f(pf[7]);
      lsum += (s01 + s23) + (s45 + s67);
#pragma unroll
      for (int j = 0; j < 4; ++j) {
        int rb = 32 * j + lo;
        bf16x8 vf = *(const bf16x8*)&Bt[rb * 64 + (((2*kk + hi) ^ (rb & 7)) * 8)];
        acc[j] = __builtin_amdgcn_mfma_f32_32x32x16_bf16(pf, vf, acc[j], 0, 0, 0);
      }
    }
    __builtin_amdgcn_s_setprio(0);
  }

  // full row-sum: combine the two hi-halves (lane ^ 32 holds the other half)
  lsum += __shfl_xor(lsum, 32);
  if (hi == 0) lB[wv][lo] = lsum;   // row t = ti*128 + 32wv + lo
  asm volatile("s_waitcnt lgkmcnt(0)" ::: "memory");

  // epilogue: O[t][d] = acc / l[t];  32 lanes x 4B contiguous per (j,r)
#pragma unroll
  for (int r = 0; r < 16; ++r) {
    int crow = (r & 3) + 8 * (r >> 2) + 4 * hi;
    float inv = 1.0f / lB[wv][crow];
    int t = ti * 128 + 32 * wv + crow;
#pragma unroll
    for (int j = 0; j < 4; ++j) {
      Oh[(size_t)t * D_ + di * 128 + 32 * j + lo] = acc[j][r] * inv;
    }
  }
}

extern "C" void kernel_launch(void* const* d_in, const int* in_sizes, int n_in,
                              void* d_out, int out_size, void* d_ws, size_t ws_size,
                              hipStream_t stream) {
  const float* Q     = (const float*)d_in[0];
  const float* V     = (const float*)d_in[1];
  const float* freqs = (const float*)d_in[2];
  float* Out = (float*)d_out;

  // ws layout: tab 1MB | KR 48MB | VT 48MB | P 96MB  (total 193MB)
  float2* tab  = (float2*)d_ws;
  ushort_t* KR = (ushort_t*)((char*)d_ws + (1 << 20));
  ushort_t* VT = (ushort_t*)((char*)d_ws + (1 << 20) + (size_t)NBH * T_ * D_ * 2);
  ushort_t* P  = (ushort_t*)((char*)d_ws + (1 << 20) + (size_t)2 * NBH * T_ * D_ * 2);

  tab_kernel<<<(T_ * (D_/2) + 255) / 256, 256, 0, stream>>>(freqs, tab);
  kr_kernel<<<NBH * T_ / 8, 256, 0, stream>>>(Q, tab, KR);
  vt_kernel<<<NBH * 16 * 4, 256, 0, stream>>>(V, VT);

  for (int g = 0; g < NG; ++g) {
    const ushort_t* KRg = KR + (size_t)g * GRP * T_ * D_;
    const ushort_t* VTg = VT + (size_t)g * GRP * D_ * T_;
    float* Og = Out + (size_t)g * GRP * T_ * D_;
    gemm1_kernel<<<G1BLK, 256, 0, stream>>>(KRg, P);
    gemm2_kernel<<<G2BLK, 256, 0, stream>>>(P, VTg, Og);
  }
}

// Round 9
// 235.806 us; speedup vs baseline: 2.2580x; 1.1111x over previous
//
#include <hip/hip_runtime.h>
#include <hip/hip_bf16.h>
#include <stdint.h>

#define B_ 8
#define NH_ 12
#define NBH (B_*NH_)       // 96
#define T_ 1024
#define D_ 256

typedef __attribute__((ext_vector_type(8))) short bf16x8;
typedef __attribute__((ext_vector_type(16))) float f32x16;
typedef unsigned short ushort_t;

#define Z16 ((f32x16){0,0,0,0,0,0,0,0,0,0,0,0,0,0,0,0})

// KR pre-scale: 0.25 * sqrt(log2(e)) so that (KR.KR^T) = (S/sqrt(256)) * log2(e)
#define KSCALE 0.30028060218f

__device__ __forceinline__ short f2bf(float x) {
  __hip_bfloat16 h = __float2bfloat16(x);
  return *reinterpret_cast<short*>(&h);
}
__device__ __forceinline__ float bf2f(short x) {
  unsigned int u = ((unsigned int)(unsigned short)x) << 16;
  return __uint_as_float(u);
}
__device__ __forceinline__ void gload16(const ushort_t* g, ushort_t* l) {
  __builtin_amdgcn_global_load_lds(
      (const __attribute__((address_space(1))) uint32_t*)g,
      (__attribute__((address_space(3))) uint32_t*)l, 16, 0, 0);
}

// ---------------- prep kernels (unchanged, proven) ----------------

__global__ void tab_kernel(const float* __restrict__ freqs, float2* __restrict__ tab) {
  int idx = blockIdx.x * blockDim.x + threadIdx.x;
  if (idx >= T_ * (D_/2)) return;
  int t = idx >> 7;
  int i = idx & 127;
  float ph = (float)t * freqs[2*i];
  ph -= floorf(ph);
  float ang = ph * 6.283185307179586f;
  tab[idx] = make_float2(cosf(ang), sinf(ang));
}

__global__ __launch_bounds__(256) void kr_kernel(const float* __restrict__ Q,
                                                 const float2* __restrict__ tab,
                                                 ushort_t* __restrict__ KR) {
  int row = blockIdx.x * 8 + (threadIdx.x >> 5);
  int d8  = threadIdx.x & 31;
  int t = row & (T_ - 1);
  const float* src = Q + (size_t)row * D_ + d8 * 8;
  float4 x0 = *(const float4*)src;
  float4 x1 = *(const float4*)(src + 4);
  const float2* tr = tab + t * (D_/2) + d8 * 4;
  float2 c0 = tr[0], c1 = tr[1], c2 = tr[2], c3 = tr[3];
  bf16x8 f;
  f[0] = f2bf((x0.x * c0.x - x0.y * c0.y) * KSCALE);
  f[1] = f2bf((x0.y * c0.x + x0.x * c0.y) * KSCALE);
  f[2] = f2bf((x0.z * c1.x - x0.w * c1.y) * KSCALE);
  f[3] = f2bf((x0.w * c1.x + x0.z * c1.y) * KSCALE);
  f[4] = f2bf((x1.x * c2.x - x1.y * c2.y) * KSCALE);
  f[5] = f2bf((x1.y * c2.x + x1.x * c2.y) * KSCALE);
  f[6] = f2bf((x1.z * c3.x - x1.w * c3.y) * KSCALE);
  f[7] = f2bf((x1.w * c3.x + x1.z * c3.y) * KSCALE);
  *(bf16x8*)(KR + (size_t)row * D_ + d8 * 8) = f;
}

__global__ __launch_bounds__(256) void vt_kernel(const float* __restrict__ V,
                                                 ushort_t* __restrict__ VT) {
  int blk = blockIdx.x;
  int d64 = blk & 3, t64 = (blk >> 2) & 15, bh = blk >> 6;
  __shared__ ushort_t st[64][66];
  {
    int t = threadIdx.x >> 2, j = threadIdx.x & 3;
    const float* src = V + ((size_t)bh * T_ + t64 * 64 + t) * D_ + d64 * 64 + j * 16;
#pragma unroll
    for (int q2 = 0; q2 < 4; ++q2) {
      float4 x = *(const float4*)(src + q2 * 4);
      st[t][j*16 + q2*4 + 0] = (ushort_t)f2bf(x.x);
      st[t][j*16 + q2*4 + 1] = (ushort_t)f2bf(x.y);
      st[t][j*16 + q2*4 + 2] = (ushort_t)f2bf(x.z);
      st[t][j*16 + q2*4 + 3] = (ushort_t)f2bf(x.w);
    }
  }
  __syncthreads();
  {
    int d = threadIdx.x >> 2, tq = threadIdx.x & 3;
    bf16x8 a_, b_;
#pragma unroll
    for (int i = 0; i < 8; ++i) {
      a_[i] = (short)st[tq*16 + i][d];
      b_[i] = (short)st[tq*16 + 8 + i][d];
    }
    ushort_t* dst = VT + ((size_t)bh * D_ + d64*64 + d) * T_ + t64*64 + tq*16;
    *(bf16x8*)dst = a_;
    *(bf16x8*)(dst + 8) = b_;
  }
}

// ---------------- GEMM1: P = exp2(KR . KR^T), symmetric ----------------
// S is symmetric (same operand both sides), so only lower-triangle blocks
// (ti >= si): 36 per head instead of 64. Off-diagonal blocks write the tile
// twice — normal, and transposed via a chunk-XOR-swizzled LDS overlay of the
// (dead) staging buffers.
// Block = 128t x 128s, 4 waves, K=256 in 4 steps of BK=64.
// MFMA convention (verified r1/r3/r8): acc = mfma(A,B): col(lo) <-> B rows,
// crow(r,hi) = (r&3)+8(r>>2)+4hi <-> A rows.
__global__ __launch_bounds__(256, 4)
void gemm1_kernel(const ushort_t* __restrict__ KRg, ushort_t* __restrict__ P) {
  int bid = blockIdx.x;
  int nblk = gridDim.x;                       // nh*36, divisible by 8
  int swz = (bid & 7) * (nblk >> 3) + (bid >> 3);
  int b = swz % 36;
  int h = swz / 36;
  // triangle decode: b = ti*(ti+1)/2 + si, si <= ti  (exact in fp32 for b<36)
  int ti = (int)((sqrtf(8.0f * b + 1.0f) - 1.0f) * 0.5f);
  int si = b - ti * (ti + 1) / 2;

  const ushort_t* __restrict__ Kh = KRg + (size_t)h * (T_ * D_);
  ushort_t* __restrict__ Ph = P + (size_t)h * (T_ * T_);

  const int tid = threadIdx.x, lane = tid & 63, wv = tid >> 6;
  const int lo = lane & 31, hi = lane >> 5;

  __shared__ __align__(16) ushort_t SH[2 * 128 * 64];   // At | Bt (32 KB)
  ushort_t* At = SH;
  ushort_t* Bt = SH + 128 * 64;

  f32x16 acc[4];
#pragma unroll
  for (int j = 0; j < 4; ++j) acc[j] = Z16;

  const ushort_t* Abase = Kh + (size_t)ti * 128 * D_;
  const ushort_t* Bbase = Kh + (size_t)si * 128 * D_;

  for (int ks = 0; ks < 4; ++ks) {
    int k0 = ks * 64;
    __syncthreads();                 // WAR: previous compute done
#pragma unroll
    for (int i = 0; i < 4; ++i) {
      int d = tid + i * 256;         // chunk index 0..1023
      int r = d >> 3, c = d & 7;
      int srcoff = r * D_ + k0 + ((c ^ (r & 7)) * 8);
      gload16(Abase + srcoff, &At[d * 8]);
      gload16(Bbase + srcoff, &Bt[d * 8]);
    }
    __syncthreads();                 // RAW (includes vmcnt drain)
    __builtin_amdgcn_s_setprio(1);
#pragma unroll
    for (int kk = 0; kk < 4; ++kk) {
      int ra = 32 * wv + lo;
      bf16x8 af = *(const bf16x8*)&At[ra * 64 + (((2*kk + hi) ^ (ra & 7)) * 8)];
#pragma unroll
      for (int j = 0; j < 4; ++j) {
        int rb = 32 * j + lo;
        bf16x8 bf_ = *(const bf16x8*)&Bt[rb * 64 + (((2*kk + hi) ^ (rb & 7)) * 8)];
        acc[j] = __builtin_amdgcn_mfma_f32_32x32x16_bf16(af, bf_, acc[j], 0, 0, 0);
      }
    }
    __builtin_amdgcn_s_setprio(0);
  }

  // epilogue: pe = bf16(exp2(acc)); write normal tile (t row, s col)
  ushort_t pe[4][16];
#pragma unroll
  for (int j = 0; j < 4; ++j)
#pragma unroll
    for (int r = 0; r < 16; ++r)
      pe[j][r] = (ushort_t)f2bf(exp2f(acc[j][r]));

#pragma unroll
  for (int j = 0; j < 4; ++j) {
#pragma unroll
    for (int r = 0; r < 16; ++r) {
      int t = ti * 128 + 32 * wv + ((r & 3) + 8 * (r >> 2) + 4 * hi);
      int s = si * 128 + 32 * j + lo;
      Ph[(size_t)t * T_ + s] = pe[j][r];
    }
  }

  if (ti != si) {
    // transposed tile via LDS overlay (At/Bt dead). Layout: row = s (0..127),
    // logical chunk c (of 8 cols t) stored at chunk c ^ (s&7)  -> conflict-free
    // b128 reads; scalar writes ~4-way (one-shot, acceptable).
    __syncthreads();   // all waves done with At/Bt MFMA reads
    ushort_t* Lt = SH; // 32 KB = [128][128] bf16
#pragma unroll
    for (int j = 0; j < 4; ++j) {
#pragma unroll
      for (int r = 0; r < 16; ++r) {
        int trow = 32 * wv + ((r & 3) + 8 * (r >> 2) + 4 * hi);
        int scol = 32 * j + lo;
        int cc = (trow >> 3) ^ (scol & 7);
        Lt[scol * 128 + (cc << 3) + (trow & 7)] = pe[j][r];
      }
    }
    __syncthreads();
    // coalesced write: 16 rows x 16 chunks per pass, 8 passes
#pragma unroll
    for (int it = 0; it < 8; ++it) {
      int sr = it * 16 + (tid >> 4);
      int c  = tid & 15;
      bf16x8 vv = *(const bf16x8*)&Lt[sr * 128 + ((c ^ (sr & 7)) << 3)];
      *(bf16x8*)&Ph[(size_t)(si * 128 + sr) * T_ + ti * 128 + c * 8] = vv;
    }
  }
}

// ---------------- GEMM2: O = (P . V) / rowsum(P)  (per head) ----------------
// Block = 128t x 128d, K=1024 in 16 steps of BK=64. A = P rows(t), B = VT rows(d).
// l[t] accumulated from the same bf16 P fragments the MFMA consumes.
__global__ __launch_bounds__(256, 4)
void gemm2_kernel(const ushort_t* __restrict__ P, const ushort_t* __restrict__ VTg,
                  float* __restrict__ Og) {
  int bid = blockIdx.x;
  int nblk = gridDim.x;                       // nh*16, divisible by 8
  int swz = (bid & 7) * (nblk >> 3) + (bid >> 3);
  int di = swz & 1;
  int ti = (swz >> 1) & 7;
  int h  = swz >> 4;

  const ushort_t* __restrict__ Ph = P + (size_t)h * (T_ * T_);
  const ushort_t* __restrict__ Vh = VTg + (size_t)h * (D_ * T_);
  float* __restrict__ Oh = Og + (size_t)h * (T_ * D_);

  const int tid = threadIdx.x, lane = tid & 63, wv = tid >> 6;
  const int lo = lane & 31, hi = lane >> 5;

  __shared__ __align__(16) ushort_t At[128 * 64];   // P t-rows tile
  __shared__ __align__(16) ushort_t Bt[128 * 64];   // VT d-rows tile
  __shared__ float lB[4][32];

  f32x16 acc[4];
#pragma unroll
  for (int j = 0; j < 4; ++j) acc[j] = Z16;
  float lsum = 0.0f;

  const ushort_t* Abase = Ph + (size_t)ti * 128 * T_;
  const ushort_t* Bbase = Vh + (size_t)di * 128 * T_;

  for (int ks = 0; ks < 16; ++ks) {
    int k0 = ks * 64;
    __syncthreads();
#pragma unroll
    for (int i = 0; i < 4; ++i) {
      int d = tid + i * 256;
      int r = d >> 3, c = d & 7;
      int srcoff = r * T_ + k0 + ((c ^ (r & 7)) * 8);
      gload16(Abase + srcoff, &At[d * 8]);
      gload16(Bbase + srcoff, &Bt[d * 8]);
    }
    __syncthreads();
    __builtin_amdgcn_s_setprio(1);
#pragma unroll
    for (int kk = 0; kk < 4; ++kk) {
      int ra = 32 * wv + lo;
      bf16x8 pf = *(const bf16x8*)&At[ra * 64 + (((2*kk + hi) ^ (ra & 7)) * 8)];
      float s01 = bf2f(pf[0]) + bf2f(pf[1]);
      float s23 = bf2f(pf[2]) + bf2f(pf[3]);
      float s45 = bf2f(pf[4]) + bf2f(pf[5]);
      float s67 = bf2f(pf[6]) + bf2f(pf[7]);
      lsum += (s01 + s23) + (s45 + s67);
#pragma unroll
      for (int j = 0; j < 4; ++j) {
        int rb = 32 * j + lo;
        bf16x8 vf = *(const bf16x8*)&Bt[rb * 64 + (((2*kk + hi) ^ (rb & 7)) * 8)];
        acc[j] = __builtin_amdgcn_mfma_f32_32x32x16_bf16(pf, vf, acc[j], 0, 0, 0);
      }
    }
    __builtin_amdgcn_s_setprio(0);
  }

  // full row-sum: combine the two hi-halves (lane ^ 32 holds the other half)
  lsum += __shfl_xor(lsum, 32);
  if (hi == 0) lB[wv][lo] = lsum;   // row t = ti*128 + 32wv + lo
  asm volatile("s_waitcnt lgkmcnt(0)" ::: "memory");

  // epilogue: O[t][d] = acc / l[t];  32 lanes x 4B contiguous per (j,r)
#pragma unroll
  for (int r = 0; r < 16; ++r) {
    int crow = (r & 3) + 8 * (r >> 2) + 4 * hi;
    float inv = 1.0f / lB[wv][crow];
    int t = ti * 128 + 32 * wv + crow;
#pragma unroll
    for (int j = 0; j < 4; ++j) {
      Oh[(size_t)t * D_ + di * 128 + 32 * j + lo] = acc[j][r] * inv;
    }
  }
}

extern "C" void kernel_launch(void* const* d_in, const int* in_sizes, int n_in,
                              void* d_out, int out_size, void* d_ws, size_t ws_size,
                              hipStream_t stream) {
  const float* Q     = (const float*)d_in[0];
  const float* V     = (const float*)d_in[1];
  const float* freqs = (const float*)d_in[2];
  float* Out = (float*)d_out;

  // ws layout: tab 1MB | KR 48MB | VT 48MB | P (96 or 192 MB)
  float2* tab  = (float2*)d_ws;
  ushort_t* KR = (ushort_t*)((char*)d_ws + (1 << 20));
  ushort_t* VT = (ushort_t*)((char*)d_ws + (1 << 20) + (size_t)NBH * T_ * D_ * 2);
  ushort_t* P  = (ushort_t*)((char*)d_ws + (1 << 20) + (size_t)2 * NBH * T_ * D_ * 2);

  tab_kernel<<<(T_ * (D_/2) + 255) / 256, 256, 0, stream>>>(freqs, tab);
  kr_kernel<<<NBH * T_ / 8, 256, 0, stream>>>(Q, tab, KR);
  vt_kernel<<<NBH * 16 * 4, 256, 0, stream>>>(V, VT);

  size_t base = (1 << 20) + (size_t)2 * NBH * T_ * D_ * 2;       // 97 MB
  size_t need1 = base + (size_t)NBH * T_ * T_ * 2;               // +192 MB
  int ng = (ws_size >= need1) ? 1 : 2;                           // fall back to 2 groups
  int hg = NBH / ng;

  for (int g = 0; g < ng; ++g) {
    const ushort_t* KRg = KR + (size_t)g * hg * T_ * D_;
    const ushort_t* VTg = VT + (size_t)g * hg * D_ * T_;
    float* Og = Out + (size_t)g * hg * T_ * D_;
    gemm1_kernel<<<hg * 36, 256, 0, stream>>>(KRg, P);
    gemm2_kernel<<<hg * 16, 256, 0, stream>>>(P, VTg, Og);
  }
}